// Round 4
// baseline (395.194 us; speedup 1.0000x reference)
//
#include <hip/hip_runtime.h>
#include <hip/hip_bf16.h>
#include <math.h>

#define B_SZ   1024
#define NROW   2048      // 2B
#define D_K    16384     // 128*128
#define TEMP_INV 2.0f    // 1/0.5
#define SPLIT  8
#define KSEG   (D_K / SPLIT)
#define NTILE  16        // 2048/128
#define NPAIR  136       // NTILE*(NTILE+1)/2

typedef short bf16x8 __attribute__((ext_vector_type(8)));
typedef float f32x4  __attribute__((ext_vector_type(4)));
typedef unsigned short u16x4 __attribute__((ext_vector_type(4)));

typedef __attribute__((address_space(1))) unsigned int GU32;
typedef __attribute__((address_space(3))) unsigned int LU32;

__device__ __forceinline__ void async16(const void* g, void* l) {
  __builtin_amdgcn_global_load_lds((GU32*)(g), (LU32*)(l), 16, 0, 0);
}

// fp32 -> bf16 bits, round-to-nearest-even (finite inputs)
__device__ __forceinline__ unsigned short f2bf(float f) {
  unsigned int u = __float_as_uint(f);
  u += 0x7fffu + ((u >> 16) & 1u);
  return (unsigned short)(u >> 16);
}

// ---------------------------------------------------------------------------
// Kernel 1: per-row normalize -> bf16 rn[2048][16384]; zero sim + acc/cnt.
// ---------------------------------------------------------------------------
__global__ __launch_bounds__(256) void norm_kernel(
    const float* __restrict__ emb_i, const float* __restrict__ emb_j,
    __hip_bfloat16* __restrict__ rn, float* __restrict__ sim,
    float* __restrict__ acc_sum, unsigned int* __restrict__ acc_cnt)
{
  const int b = blockIdx.x;
  const int t = threadIdx.x;
  const int c = t & 31;        // column group (4 cols)
  const int g = t >> 5;        // row group (16 rows)

  // stripe-zero sim: 2048 blocks x 256 thr x 2 float4 = 16 MB exactly
  {
    f32x4* sz = (f32x4*)sim + (size_t)b * 512 + t * 2;
    sz[0] = (f32x4){0.f, 0.f, 0.f, 0.f};
    sz[1] = (f32x4){0.f, 0.f, 0.f, 0.f};
  }
  if (b == 0 && t == 0) { *acc_sum = 0.f; *acc_cnt = 0u; }

  const float* src = (b < B_SZ) ? (emb_i + (size_t)b * D_K)
                                : (emb_j + (size_t)(b - B_SZ) * D_K);

  f32x4 vals[16];
  f32x4 ss = (f32x4){0.f, 0.f, 0.f, 0.f};
#pragma unroll
  for (int mm = 0; mm < 16; ++mm) {
    f32x4 v = *(const f32x4*)(src + (size_t)(g * 16 + mm) * 128 + c * 4);
    vals[mm] = v;
    ss += v * v;
  }

  __shared__ f32x4 part[8][32];
  part[g][c] = ss;
  __syncthreads();
  f32x4 css = part[0][c];
#pragma unroll
  for (int gg = 1; gg < 8; ++gg) css += part[gg][c];

  f32x4 mcn, colz2;
#pragma unroll
  for (int k = 0; k < 4; ++k) {
    mcn[k] = fmaxf(sqrtf(css[k]), 1e-12f);
    colz2[k] = css[k] / (mcn[k] * mcn[k]);
  }
  // each wave holds every c twice -> wave sum = 2 * rowss
  float s = colz2[0] + colz2[1] + colz2[2] + colz2[3];
#pragma unroll
  for (int off = 1; off < 64; off <<= 1) s += __shfl_xor(s, off);
  const float rowss = 0.5f * s;
  const float rowfac = fmaxf(sqrtf(rowss), 1e-8f);

  f32x4 scale;
#pragma unroll
  for (int k = 0; k < 4; ++k) scale[k] = 1.f / (mcn[k] * rowfac);

  __hip_bfloat16* dst = rn + (size_t)b * D_K;
#pragma unroll
  for (int mm = 0; mm < 16; ++mm) {
    f32x4 sv = vals[mm] * scale;
    u16x4 o;
#pragma unroll
    for (int k = 0; k < 4; ++k)
      o[k] = f2bf(sv[k]);
    *(u16x4*)(dst + (size_t)(g * 16 + mm) * 128 + c * 4) = o;
  }
}

// ---------------------------------------------------------------------------
// Kernel 2: sim(upper) += rn @ rn^T  (bf16 MFMA, symmetric: tiles tI<=tJ only)
// Grid (136, SPLIT); 256 threads = 4 waves (2x2 of 64x64 subtiles), BK=32.
// ---------------------------------------------------------------------------
__global__ __launch_bounds__(256) void gemm_sim_kernel(
    const __hip_bfloat16* __restrict__ rn, float* __restrict__ sim)
{
  // decode upper-triangular tile pair
  int idx = blockIdx.x, tI = 0, rem = NTILE;
  while (idx >= rem) { idx -= rem; --rem; ++tI; }
  const int tJ = tI + idx;
  const bool diag = (tI == tJ);

  const int kBase = blockIdx.y * KSEG;
  const int t    = threadIdx.x;
  const int lane = t & 63;
  const int wave = t >> 6;
  const int wm = wave >> 1, wn = wave & 1;
  const int quad = lane >> 4, col = lane & 15;

  __shared__ __align__(16) short As[128 * 32];
  __shared__ __align__(16) short Bs[128 * 32];

  const short* rnS = (const short*)rn;
  const short* aG = rnS + (size_t)(tI * 128 + (t >> 2)) * D_K + kBase + (t & 3) * 8;
  const short* bG = rnS + (size_t)(tJ * 128 + (t >> 2)) * D_K + kBase + (t & 3) * 8;
  short* aL0 = &As[t * 8];
  short* aL1 = &As[2048 + t * 8];
  short* bL0 = &Bs[t * 8];
  short* bL1 = &Bs[2048 + t * 8];
  const size_t half = (size_t)64 * D_K;

  f32x4 acc[4][4];
#pragma unroll
  for (int mi = 0; mi < 4; ++mi)
#pragma unroll
    for (int ni = 0; ni < 4; ++ni)
      acc[mi][ni] = (f32x4){0.f, 0.f, 0.f, 0.f};

  const short* aLr = &As[(wm * 64 + col) * 32 + quad * 8];
  const short* bLr = &Bs[(wn * 64 + col) * 32 + quad * 8];

  for (int k0 = 0; k0 < KSEG; k0 += 32) {
    __syncthreads();
    async16(aG + k0, aL0);
    async16(aG + half + k0, aL1);
    async16(bG + k0, bL0);
    async16(bG + half + k0, bL1);
    __syncthreads();

    bf16x8 af[4], bf[4];
#pragma unroll
    for (int mi = 0; mi < 4; ++mi) af[mi] = *(const bf16x8*)(aLr + mi * 16 * 32);
#pragma unroll
    for (int ni = 0; ni < 4; ++ni) bf[ni] = *(const bf16x8*)(bLr + ni * 16 * 32);
#pragma unroll
    for (int mi = 0; mi < 4; ++mi)
#pragma unroll
      for (int ni = 0; ni < 4; ++ni)
        acc[mi][ni] = __builtin_amdgcn_mfma_f32_16x16x32_bf16(
            af[mi], bf[ni], acc[mi][ni], 0, 0, 0);
  }

  // C/D layout: col=lane&15, row=quad*4+reg. Off-diag tiles: all j > i.
  const int iB = tI * 128 + wm * 64;
  const int jB = tJ * 128 + wn * 64;
#pragma unroll
  for (int mi = 0; mi < 4; ++mi) {
#pragma unroll
    for (int reg = 0; reg < 4; ++reg) {
      const int i = iB + mi * 16 + quad * 4 + reg;
#pragma unroll
      for (int ni = 0; ni < 4; ++ni) {
        const int j = jB + ni * 16 + col;
        if (!diag || j >= i)
          atomicAdd(&sim[(size_t)i * NROW + j], acc[mi][ni][reg]);
      }
    }
  }
}

// ---------------------------------------------------------------------------
// Kernel 3: per-row NT-Xent + grid-wide reduction (upper-triangle storage).
// loss = (1/2B) * sum_i [ log(sum_{j!=i} e^{2 sim_ij}) - 2 pos_i ]
// ---------------------------------------------------------------------------
__global__ __launch_bounds__(256) void loss_kernel(
    const float* __restrict__ sim, float* __restrict__ acc_sum,
    unsigned int* __restrict__ acc_cnt, float* __restrict__ out)
{
  const int i = blockIdx.x;
  const int t = threadIdx.x;

  float s = 0.f;
#pragma unroll
  for (int rep = 0; rep < 8; ++rep) {
    const int j = t + rep * 256;
    const float v = (j >= i) ? sim[(size_t)i * NROW + j]
                             : sim[(size_t)j * NROW + i];
    s += (j == i) ? 0.f : __expf(TEMP_INV * v);
  }
#pragma unroll
  for (int off = 1; off < 64; off <<= 1) s += __shfl_xor(s, off);
  __shared__ float r[4];
  if ((t & 63) == 0) r[t >> 6] = s;
  __syncthreads();
  if (t == 0) {
    const float denom = r[0] + r[1] + r[2] + r[3];
    const int jp = (i < B_SZ) ? i + B_SZ : i - B_SZ;
    const float pos = (jp >= i) ? sim[(size_t)i * NROW + jp]
                                : sim[(size_t)jp * NROW + i];
    const float rowval = logf(denom) - TEMP_INV * pos;
    atomicAdd(acc_sum, rowval);
    __threadfence();
    const unsigned int old = atomicAdd(acc_cnt, 1u);
    if (old == NROW - 1) {
      __threadfence();
      const float total = atomicAdd(acc_sum, 0.f);  // coherent read
      out[0] = total * (1.0f / NROW);
    }
  }
}

extern "C" void kernel_launch(void* const* d_in, const int* in_sizes, int n_in,
                              void* d_out, int out_size, void* d_ws, size_t ws_size,
                              hipStream_t stream) {
  const float* emb_i = (const float*)d_in[0];
  const float* emb_j = (const float*)d_in[1];
  float* out = (float*)d_out;

  char* ws = (char*)d_ws;
  __hip_bfloat16* rn = (__hip_bfloat16*)ws;                          // 64 MB
  float* sim = (float*)(ws + (size_t)NROW * D_K * sizeof(short));    // 16 MB
  float* acc_sum = sim + (size_t)NROW * NROW;
  unsigned int* acc_cnt = (unsigned int*)(acc_sum + 1);

  norm_kernel<<<dim3(NROW), dim3(256), 0, stream>>>(emb_i, emb_j, rn, sim,
                                                    acc_sum, acc_cnt);
  gemm_sim_kernel<<<dim3(NPAIR, SPLIT), dim3(256), 0, stream>>>(rn, sim);
  loss_kernel<<<dim3(NROW), dim3(256), 0, stream>>>(sim, acc_sum, acc_cnt, out);
}

// Round 5
// 288.635 us; speedup vs baseline: 1.3692x; 1.3692x over previous
//
#include <hip/hip_runtime.h>
#include <hip/hip_bf16.h>
#include <math.h>

#define B_SZ   1024
#define NROW   2048      // 2B
#define D_K    16384     // 128*128
#define TEMP_INV 2.0f    // 1/0.5
#define SPLIT  8
#define KSEG   (D_K / SPLIT)   // 2048
#define NTILE  16        // 2048/128
#define NPAIR  136       // NTILE*(NTILE+1)/2

typedef float f32x4 __attribute__((ext_vector_type(4)));
typedef long  i64;

typedef __attribute__((address_space(1))) unsigned int GU32;
typedef __attribute__((address_space(3))) unsigned int LU32;

__device__ __forceinline__ void async16(const void* g, void* l) {
  __builtin_amdgcn_global_load_lds((GU32*)(g), (LU32*)(l), 16, 0, 0);
}

// ---------------------------------------------------------------------------
// Kernel 1: per-row normalize -> fp8 e4m3 rn[2048][16384]; zero sim + rsum.
// ---------------------------------------------------------------------------
__global__ __launch_bounds__(256) void norm_kernel(
    const float* __restrict__ emb_i, const float* __restrict__ emb_j,
    unsigned char* __restrict__ rn, float* __restrict__ sim,
    float* __restrict__ rsum)
{
  const int b = blockIdx.x;
  const int t = threadIdx.x;
  const int c = t & 31;        // column group (4 cols)
  const int g = t >> 5;        // row group (16 rows)

  // stripe-zero sim: 2048 blocks x 256 thr x 2 float4 = 16 MB exactly
  {
    f32x4* sz = (f32x4*)sim + (size_t)b * 512 + t * 2;
    sz[0] = (f32x4){0.f, 0.f, 0.f, 0.f};
    sz[1] = (f32x4){0.f, 0.f, 0.f, 0.f};
  }
  if (b == 0) {
    for (int k = t; k < NROW; k += 256) rsum[k] = 0.f;
  }

  const float* src = (b < B_SZ) ? (emb_i + (size_t)b * D_K)
                                : (emb_j + (size_t)(b - B_SZ) * D_K);

  f32x4 vals[16];
  f32x4 ss = (f32x4){0.f, 0.f, 0.f, 0.f};
#pragma unroll
  for (int mm = 0; mm < 16; ++mm) {
    f32x4 v = *(const f32x4*)(src + (size_t)(g * 16 + mm) * 128 + c * 4);
    vals[mm] = v;
    ss += v * v;
  }

  __shared__ f32x4 part[8][32];
  part[g][c] = ss;
  __syncthreads();
  f32x4 css = part[0][c];
#pragma unroll
  for (int gg = 1; gg < 8; ++gg) css += part[gg][c];

  f32x4 mcn, colz2;
#pragma unroll
  for (int k = 0; k < 4; ++k) {
    mcn[k] = fmaxf(sqrtf(css[k]), 1e-12f);
    colz2[k] = css[k] / (mcn[k] * mcn[k]);
  }
  // each wave holds every c twice -> wave sum = 2 * rowss
  float s = colz2[0] + colz2[1] + colz2[2] + colz2[3];
#pragma unroll
  for (int off = 1; off < 64; off <<= 1) s += __shfl_xor(s, off);
  const float rowss = 0.5f * s;
  const float rowfac = fmaxf(sqrtf(rowss), 1e-8f);

  f32x4 scale;
#pragma unroll
  for (int k = 0; k < 4; ++k) scale[k] = 1.f / (mcn[k] * rowfac);

  unsigned char* dst = rn + (size_t)b * D_K;
#pragma unroll
  for (int mm = 0; mm < 16; ++mm) {
    f32x4 sv = vals[mm] * scale;
    int p = 0;
    p = __builtin_amdgcn_cvt_pk_fp8_f32(sv[0], sv[1], p, false);
    p = __builtin_amdgcn_cvt_pk_fp8_f32(sv[2], sv[3], p, true);
    *(int*)(dst + (size_t)(g * 16 + mm) * 128 + c * 4) = p;
  }
}

// ---------------------------------------------------------------------------
// Kernel 2: sim(upper) += rn @ rn^T  (fp8 MFMA, symmetric tiles tI<=tJ)
// Grid (SPLIT, 136): linear id % 8 == split -> each XCD owns one K-segment
// (4 MB working set = one L2). 256 thr = 4 waves (2x2 of 64x64), BK=32.
// ---------------------------------------------------------------------------
__global__ __launch_bounds__(256) void gemm_sim_kernel(
    const unsigned char* __restrict__ rn, float* __restrict__ sim)
{
  int idx = blockIdx.y, tI = 0, rem = NTILE;
  while (idx >= rem) { idx -= rem; --rem; ++tI; }
  const int tJ = tI + idx;
  const bool diag = (tI == tJ);

  const int kBase = blockIdx.x * KSEG;
  const int t    = threadIdx.x;
  const int lane = t & 63;
  const int wave = t >> 6;
  const int wm = wave >> 1, wn = wave & 1;
  const int quad = lane >> 4, col = lane & 15;

  __shared__ __align__(16) unsigned char As[128 * 32];  // 128 rows x 32 fp8
  __shared__ __align__(16) unsigned char Bs[128 * 32];

  // staging: thread t loads 16B: row = t>>1, kchunk = (t&1)*16
  const unsigned char* aG = rn + (size_t)(tI * 128 + (t >> 1)) * D_K + kBase + (t & 1) * 16;
  const unsigned char* bG = rn + (size_t)(tJ * 128 + (t >> 1)) * D_K + kBase + (t & 1) * 16;
  unsigned char* aL = &As[t * 16];
  unsigned char* bL = &Bs[t * 16];

  f32x4 acc[4][4];
#pragma unroll
  for (int mi = 0; mi < 4; ++mi)
#pragma unroll
    for (int ni = 0; ni < 4; ++ni)
      acc[mi][ni] = (f32x4){0.f, 0.f, 0.f, 0.f};

  // fragment: A[m=lane&15][k=quad*8+j], 8 fp8 = 8B per lane
  const unsigned char* aLr = &As[(wm * 64 + col) * 32 + quad * 8];
  const unsigned char* bLr = &Bs[(wn * 64 + col) * 32 + quad * 8];

  for (int k0 = 0; k0 < KSEG; k0 += 32) {
    __syncthreads();
    async16(aG + k0, aL);
    async16(bG + k0, bL);
    __syncthreads();

    i64 af[4], bf[4];
#pragma unroll
    for (int mi = 0; mi < 4; ++mi) af[mi] = *(const i64*)(aLr + mi * 16 * 32);
#pragma unroll
    for (int ni = 0; ni < 4; ++ni) bf[ni] = *(const i64*)(bLr + ni * 16 * 32);
#pragma unroll
    for (int mi = 0; mi < 4; ++mi)
#pragma unroll
      for (int ni = 0; ni < 4; ++ni)
        acc[mi][ni] = __builtin_amdgcn_mfma_f32_16x16x32_fp8_fp8(
            af[mi], bf[ni], acc[mi][ni], 0, 0, 0);
  }

  // C/D layout: col=lane&15, row=quad*4+reg. Diag tiles: only j >= i stored.
  const int iB = tI * 128 + wm * 64;
  const int jB = tJ * 128 + wn * 64;
#pragma unroll
  for (int mi = 0; mi < 4; ++mi) {
#pragma unroll
    for (int reg = 0; reg < 4; ++reg) {
      const int i = iB + mi * 16 + quad * 4 + reg;
#pragma unroll
      for (int ni = 0; ni < 4; ++ni) {
        const int j = jB + ni * 16 + col;
        if (!diag || j >= i)
          atomicAdd(&sim[(size_t)i * NROW + j], acc[mi][ni][reg]);
      }
    }
  }
}

// ---------------------------------------------------------------------------
// Kernel 3: tile-based exp-sum. Block = upper tile (tI,tJ). Coalesced row
// reads only; each element's exp feeds rsum[i] (wave reduce) and rsum[j]
// (LDS column reduce) — symmetry on the read side. Diag: j>i only, no j==i.
// ---------------------------------------------------------------------------
__global__ __launch_bounds__(256) void loss_tile_kernel(
    const float* __restrict__ sim, float* __restrict__ rsum)
{
  int idx = blockIdx.x, tI = 0, rem = NTILE;
  while (idx >= rem) { idx -= rem; --rem; ++tI; }
  const int tJ = tI + idx;
  const bool diag = (tI == tJ);

  const int t   = threadIdx.x;
  const int w   = t >> 6;          // wave: rows w*32..w*32+31
  const int l   = t & 63;
  const int hf  = l >> 5;          // which of 2 rows per step
  const int sub = l & 31;          // covers cols sub*4..sub*4+3
  const int jb  = tJ * 128 + sub * 4;

  float ca[4] = {0.f, 0.f, 0.f, 0.f};

#pragma unroll
  for (int step = 0; step < 16; ++step) {
    const int r  = w * 32 + step * 2 + hf;
    const int gi = tI * 128 + r;
    f32x4 v = *(const f32x4*)(sim + (size_t)gi * NROW + jb);
    float e[4];
#pragma unroll
    for (int k = 0; k < 4; ++k) {
      e[k] = __expf(TEMP_INV * v[k]);
      if (diag && (jb + k <= gi)) e[k] = 0.f;   // mask lower + diagonal
      ca[k] += e[k];
    }
    float rp = e[0] + e[1] + e[2] + e[3];
#pragma unroll
    for (int off = 1; off < 32; off <<= 1) rp += __shfl_xor(rp, off);
    if (sub == 0) atomicAdd(&rsum[gi], rp);
  }

  __shared__ float colacc[8][128];
#pragma unroll
  for (int k = 0; k < 4; ++k) colacc[w * 2 + hf][sub * 4 + k] = ca[k];
  __syncthreads();
  if (t < 128) {
    float s = 0.f;
#pragma unroll
    for (int q = 0; q < 8; ++q) s += colacc[q][t];
    atomicAdd(&rsum[tJ * 128 + t], s);   // mirror contribution (row j)
  }
}

// ---------------------------------------------------------------------------
// Kernel 4: loss = (1/2B) * sum_i [ log(rsum_i) - 2*pos_i ]
// ---------------------------------------------------------------------------
__global__ __launch_bounds__(256) void final_kernel(
    const float* __restrict__ sim, const float* __restrict__ rsum,
    float* __restrict__ out)
{
  const int t = threadIdx.x;
  float s = 0.f;
  for (int i = t; i < NROW; i += 256) {
    const int jp = (i < B_SZ) ? i + B_SZ : i - B_SZ;
    const float pos = (jp >= i) ? sim[(size_t)i * NROW + jp]
                                : sim[(size_t)jp * NROW + i];
    s += logf(rsum[i]) - TEMP_INV * pos;
  }
#pragma unroll
  for (int off = 1; off < 64; off <<= 1) s += __shfl_xor(s, off);
  __shared__ float r[4];
  if ((t & 63) == 0) r[t >> 6] = s;
  __syncthreads();
  if (t == 0) out[0] = (r[0] + r[1] + r[2] + r[3]) * (1.0f / NROW);
}

extern "C" void kernel_launch(void* const* d_in, const int* in_sizes, int n_in,
                              void* d_out, int out_size, void* d_ws, size_t ws_size,
                              hipStream_t stream) {
  const float* emb_i = (const float*)d_in[0];
  const float* emb_j = (const float*)d_in[1];
  float* out = (float*)d_out;

  char* ws = (char*)d_ws;
  unsigned char* rn = (unsigned char*)ws;                 // 32 MB (fp8)
  float* sim  = (float*)(ws + (size_t)NROW * D_K);        // 16 MB
  float* rsum = sim + (size_t)NROW * NROW;                // 8 KB

  norm_kernel<<<dim3(NROW), dim3(256), 0, stream>>>(emb_i, emb_j, rn, sim, rsum);
  gemm_sim_kernel<<<dim3(SPLIT, NPAIR), dim3(256), 0, stream>>>(rn, sim);
  loss_tile_kernel<<<dim3(NPAIR), dim3(256), 0, stream>>>(sim, rsum);
  final_kernel<<<1, 256, 0, stream>>>(sim, rsum, out);
}

// Round 6
// 286.435 us; speedup vs baseline: 1.3797x; 1.0077x over previous
//
#include <hip/hip_runtime.h>
#include <hip/hip_bf16.h>
#include <math.h>

#define B_SZ   1024
#define NROW   2048      // 2B
#define D_K    16384     // 128*128
#define SPLIT  8
#define KSEG   (D_K / SPLIT)   // 2048
#define NTILE  16        // 2048/128
#define NPAIR  136       // NTILE*(NTILE+1)/2
// fp8 rows scaled by 16 each => sim holds 256 * true_sim.
// loss uses exp(sim/(0.5*256)) = exp(sim * TEMP_SIM)
#define TEMP_SIM (2.0f / 256.0f)

typedef float f32x4 __attribute__((ext_vector_type(4)));
typedef long  i64;

typedef __attribute__((address_space(1))) unsigned int GU32;
typedef __attribute__((address_space(3))) unsigned int LU32;

__device__ __forceinline__ void async16(const void* g, void* l) {
  __builtin_amdgcn_global_load_lds((GU32*)(g), (LU32*)(l), 16, 0, 0);
}

// ---------------------------------------------------------------------------
// Kernel 1: per-row normalize -> fp8 e4m3 (x16) rn[2048][16384]; zero sim/rsum.
// 512 threads: vals[8] f32x4 = 32 VGPRs/thread (was 64 with 256 thr).
// ---------------------------------------------------------------------------
__global__ __launch_bounds__(512) void norm_kernel(
    const float* __restrict__ emb_i, const float* __restrict__ emb_j,
    unsigned char* __restrict__ rn, float* __restrict__ sim,
    float* __restrict__ rsum, unsigned int* __restrict__ cnt)
{
  const int b = blockIdx.x;
  const int t = threadIdx.x;
  const int c = t & 31;        // column group (4 cols)
  const int g = t >> 5;        // row group (8 rows), 0..15

  // stripe-zero sim: 2048 blocks x 512 thr x 1 float4 = 16 MB exactly
  ((f32x4*)sim)[(size_t)b * 512 + t] = (f32x4){0.f, 0.f, 0.f, 0.f};
  if (b == 0) {
    for (int k = t; k < NROW; k += 512) rsum[k] = 0.f;
    if (t == 0) *cnt = 0u;
  }

  const float* src = (b < B_SZ) ? (emb_i + (size_t)b * D_K)
                                : (emb_j + (size_t)(b - B_SZ) * D_K);

  f32x4 vals[8];
  f32x4 ss = (f32x4){0.f, 0.f, 0.f, 0.f};
#pragma unroll
  for (int mm = 0; mm < 8; ++mm) {
    f32x4 v = *(const f32x4*)(src + (size_t)(g * 8 + mm) * 128 + c * 4);
    vals[mm] = v;
    ss += v * v;
  }

  __shared__ f32x4 part[16][32];
  part[g][c] = ss;
  __syncthreads();
  f32x4 css = part[0][c];
#pragma unroll
  for (int gg = 1; gg < 16; ++gg) css += part[gg][c];

  f32x4 mcn, colz2;
#pragma unroll
  for (int k = 0; k < 4; ++k) {
    mcn[k] = fmaxf(sqrtf(css[k]), 1e-12f);
    colz2[k] = css[k] / (mcn[k] * mcn[k]);
  }
  // every wave covers each c exactly twice -> wave sum = 2 * rowss
  float s = colz2[0] + colz2[1] + colz2[2] + colz2[3];
#pragma unroll
  for (int off = 1; off < 64; off <<= 1) s += __shfl_xor(s, off);
  const float rowfac = fmaxf(sqrtf(0.5f * s), 1e-8f);

  f32x4 scale;
#pragma unroll
  for (int k = 0; k < 4; ++k) scale[k] = 16.0f / (mcn[k] * rowfac);

  unsigned char* dst = rn + (size_t)b * D_K;
#pragma unroll
  for (int mm = 0; mm < 8; ++mm) {
    f32x4 sv = vals[mm] * scale;
    int p = 0;
    p = __builtin_amdgcn_cvt_pk_fp8_f32(sv[0], sv[1], p, false);
    p = __builtin_amdgcn_cvt_pk_fp8_f32(sv[2], sv[3], p, true);
    *(int*)(dst + (size_t)(g * 8 + mm) * 128 + c * 4) = p;
  }
}

// ---------------------------------------------------------------------------
// Kernel 2: sim(upper) += rn @ rn^T  (fp8 MFMA, BK=64: 32 MFMA per barrier)
// Grid (SPLIT, 136): linear id % 8 == split -> each XCD owns one K-segment.
// ---------------------------------------------------------------------------
__global__ __launch_bounds__(256) void gemm_sim_kernel(
    const unsigned char* __restrict__ rn, float* __restrict__ sim)
{
  int idx = blockIdx.y, tI = 0, rem = NTILE;
  while (idx >= rem) { idx -= rem; --rem; ++tI; }
  const int tJ = tI + idx;
  const bool diag = (tI == tJ);

  const int kBase = blockIdx.x * KSEG;
  const int t    = threadIdx.x;
  const int lane = t & 63;
  const int wave = t >> 6;
  const int wm = wave >> 1, wn = wave & 1;
  const int quad = lane >> 4, col = lane & 15;

  __shared__ __align__(16) unsigned char As[2][128 * 32];
  __shared__ __align__(16) unsigned char Bs[2][128 * 32];

  // staging: thread t loads 16B: row = t>>1, sub-chunk = (t&1)*16
  const unsigned char* aG = rn + (size_t)(tI * 128 + (t >> 1)) * D_K + kBase + (t & 1) * 16;
  const unsigned char* bG = rn + (size_t)(tJ * 128 + (t >> 1)) * D_K + kBase + (t & 1) * 16;
  unsigned char* aL0 = &As[0][t * 16];
  unsigned char* aL1 = &As[1][t * 16];
  unsigned char* bL0 = &Bs[0][t * 16];
  unsigned char* bL1 = &Bs[1][t * 16];

  f32x4 acc[4][4];
#pragma unroll
  for (int mi = 0; mi < 4; ++mi)
#pragma unroll
    for (int ni = 0; ni < 4; ++ni)
      acc[mi][ni] = (f32x4){0.f, 0.f, 0.f, 0.f};

  const int aOff = (wm * 64 + col) * 32 + quad * 8;
  const int bOff = (wn * 64 + col) * 32 + quad * 8;

  for (int k0 = 0; k0 < KSEG; k0 += 64) {
    __syncthreads();
    async16(aG + k0,      aL0);
    async16(aG + k0 + 32, aL1);
    async16(bG + k0,      bL0);
    async16(bG + k0 + 32, bL1);
    __syncthreads();

#pragma unroll
    for (int h = 0; h < 2; ++h) {
      i64 af[4], bf[4];
#pragma unroll
      for (int mi = 0; mi < 4; ++mi) af[mi] = *(const i64*)(&As[h][aOff + mi * 16 * 32]);
#pragma unroll
      for (int ni = 0; ni < 4; ++ni) bf[ni] = *(const i64*)(&Bs[h][bOff + ni * 16 * 32]);
#pragma unroll
      for (int mi = 0; mi < 4; ++mi)
#pragma unroll
        for (int ni = 0; ni < 4; ++ni)
          acc[mi][ni] = __builtin_amdgcn_mfma_f32_16x16x32_fp8_fp8(
              af[mi], bf[ni], acc[mi][ni], 0, 0, 0);
    }
  }

  // C/D layout: col=lane&15, row=quad*4+reg. Diag tiles: only j >= i stored.
  const int iB = tI * 128 + wm * 64;
  const int jB = tJ * 128 + wn * 64;
#pragma unroll
  for (int mi = 0; mi < 4; ++mi) {
#pragma unroll
    for (int reg = 0; reg < 4; ++reg) {
      const int i = iB + mi * 16 + quad * 4 + reg;
#pragma unroll
      for (int ni = 0; ni < 4; ++ni) {
        const int j = jB + ni * 16 + col;
        if (!diag || j >= i)
          atomicAdd(&sim[(size_t)i * NROW + j], acc[mi][ni][reg]);
      }
    }
  }
}

// ---------------------------------------------------------------------------
// Kernel 3: tile exp-sum (upper tiles, symmetric scatter) + fused finalize.
// Last block (completion counter) computes loss from rsum + positives.
// ---------------------------------------------------------------------------
__global__ __launch_bounds__(256) void loss_tile_kernel(
    const float* __restrict__ sim, float* __restrict__ rsum,
    unsigned int* __restrict__ cnt, float* __restrict__ out)
{
  int idx = blockIdx.x, tI = 0, rem = NTILE;
  while (idx >= rem) { idx -= rem; --rem; ++tI; }
  const int tJ = tI + idx;
  const bool diag = (tI == tJ);

  const int t   = threadIdx.x;
  const int w   = t >> 6;          // wave: rows w*32..w*32+31
  const int l   = t & 63;
  const int hf  = l >> 5;          // which of 2 rows per step
  const int sub = l & 31;          // covers cols sub*4..sub*4+3
  const int jb  = tJ * 128 + sub * 4;

  float ca[4] = {0.f, 0.f, 0.f, 0.f};

#pragma unroll
  for (int step = 0; step < 16; ++step) {
    const int r  = w * 32 + step * 2 + hf;
    const int gi = tI * 128 + r;
    f32x4 v = *(const f32x4*)(sim + (size_t)gi * NROW + jb);
    float e[4];
#pragma unroll
    for (int k = 0; k < 4; ++k) {
      e[k] = __expf(TEMP_SIM * v[k]);
      if (diag && (jb + k <= gi)) e[k] = 0.f;   // mask lower + diagonal
      ca[k] += e[k];
    }
    float rp = e[0] + e[1] + e[2] + e[3];
#pragma unroll
    for (int off = 1; off < 32; off <<= 1) rp += __shfl_xor(rp, off);
    if (sub == 0) atomicAdd(&rsum[gi], rp);
  }

  __shared__ float colacc[8][128];
#pragma unroll
  for (int k = 0; k < 4; ++k) colacc[w * 2 + hf][sub * 4 + k] = ca[k];
  __syncthreads();
  if (t < 128) {
    float s = 0.f;
#pragma unroll
    for (int q = 0; q < 8; ++q) s += colacc[q][t];
    atomicAdd(&rsum[tJ * 128 + t], s);   // mirror contribution (row j)
  }

  // ---- completion-counter fused finalize ----
  __syncthreads();                 // drains this block's atomics (vmcnt(0))
  __shared__ bool last;
  if (t == 0) {
    __threadfence();
    last = (atomicAdd(cnt, 1u) == NPAIR - 1);
  }
  __syncthreads();
  if (!last) return;

  float s = 0.f;
  for (int i = t; i < NROW; i += 256) {
    const int jp = (i < B_SZ) ? i + B_SZ : i - B_SZ;
    const float pos = (jp >= i) ? sim[(size_t)i * NROW + jp]
                                : sim[(size_t)jp * NROW + i];
    const float rs = atomicAdd(&rsum[i], 0.f);   // device-coherent read
    s += logf(rs) - TEMP_SIM * pos;
  }
#pragma unroll
  for (int off = 1; off < 64; off <<= 1) s += __shfl_xor(s, off);
  __shared__ float r[4];
  if ((t & 63) == 0) r[t >> 6] = s;
  __syncthreads();
  if (t == 0) out[0] = (r[0] + r[1] + r[2] + r[3]) * (1.0f / NROW);
}

extern "C" void kernel_launch(void* const* d_in, const int* in_sizes, int n_in,
                              void* d_out, int out_size, void* d_ws, size_t ws_size,
                              hipStream_t stream) {
  const float* emb_i = (const float*)d_in[0];
  const float* emb_j = (const float*)d_in[1];
  float* out = (float*)d_out;

  char* ws = (char*)d_ws;
  unsigned char* rn = (unsigned char*)ws;                 // 32 MB (fp8)
  float* sim  = (float*)(ws + (size_t)NROW * D_K);        // 16 MB
  float* rsum = sim + (size_t)NROW * NROW;                // 8 KB
  unsigned int* cnt = (unsigned int*)(rsum + NROW);

  norm_kernel<<<dim3(NROW), dim3(512), 0, stream>>>(emb_i, emb_j, rn, sim, rsum, cnt);
  gemm_sim_kernel<<<dim3(SPLIT, NPAIR), dim3(256), 0, stream>>>(rn, sim);
  loss_tile_kernel<<<dim3(NPAIR), dim3(256), 0, stream>>>(sim, rsum, cnt, out);
}